// Round 6
// baseline (20409.749 us; speedup 1.0000x reference)
//
#include <hip/hip_runtime.h>
#include <math.h>

typedef float f4 __attribute__((ext_vector_type(4)));
typedef _Float16 f16x8 __attribute__((ext_vector_type(8)));
typedef int i4 __attribute__((ext_vector_type(4)));

#define Hdim 2048
#define Bdim 256
#define Tdim 512
#define Odim 14
#define G3   6144   // 3*Hdim

// async 16B/lane global->LDS DMA. lds dest = wave-uniform base + lane*16.
__device__ __forceinline__ void async16(const void* g, const void* l) {
    __builtin_amdgcn_global_load_lds(
        (const __attribute__((address_space(1))) unsigned int*)(unsigned long long)g,
        (__attribute__((address_space(3))) unsigned int*)(unsigned int)(unsigned long long)l,
        16, 0, 0);
}

// ---------------------------------------------------------------------------
// Prep kernels (once per launch)
// ---------------------------------------------------------------------------

__global__ void prep_gtable(const float* __restrict__ b_ih,
                            const float* __restrict__ W_ih,
                            float* __restrict__ Gt) {
    int idx = blockIdx.x * 256 + threadIdx.x;
    if (idx >= 15 * G3) return;
    int c = idx / G3, row = idx % G3;
    float v = b_ih[row];
    if (c < Odim) v += W_ih[row * Odim + c];
    Gt[idx] = v;
}

__global__ void prep_gi0(const float* __restrict__ b_ih,
                         const float* __restrict__ W_ih,
                         const float* __restrict__ target,
                         float* __restrict__ gi0) {
    int idx = blockIdx.x * 256 + threadIdx.x;
    int b = idx / G3, row = idx % G3;
    const float* x0 = target + (size_t)b * (Tdim * Odim);
    float s = b_ih[row];
    #pragma unroll
    for (int c = 0; c < Odim; ++c)
        s = fmaf(fmaxf(x0[c], 0.f), W_ih[row * Odim + c], s);
    gi0[idx] = s;
}

// W_hh (6144x2048 f32) -> hi/lo fp16 frag-major: [nt][kb][lane][8]
// n = nt*16 + (lane&15), k = kb*32 + (lane>>4)*8 + j
__global__ void prep_Bpack(const float* __restrict__ W,
                           _Float16* __restrict__ Bh, _Float16* __restrict__ Bl) {
    int idx = blockIdx.x * 256 + threadIdx.x;  // 6144*256 threads
    int n = idx >> 8, kc = idx & 255;
    const float* src = W + (size_t)n * Hdim + kc * 8;
    int kb = kc >> 2, q = kc & 3;
    int lane = (n & 15) + 16 * q;
    int nt = n >> 4;
    f16x8 vh, vl;
    #pragma unroll
    for (int j = 0; j < 8; ++j) {
        float w = src[j];
        _Float16 h = (_Float16)w;
        vh[j] = h;
        vl[j] = (_Float16)(w - (float)h);
    }
    size_t off = (((size_t)nt * 64 + kb) * 64 + lane) * 8;
    *(f16x8*)(Bh + off) = vh;
    *(f16x8*)(Bl + off) = vl;
}

// enc_hidden (256x2048 f32) -> hi/lo fp16 frag-major: [mt][kb][lane][8]
__global__ void prep_A0(const float* __restrict__ h0,
                        _Float16* __restrict__ Ah, _Float16* __restrict__ Al) {
    int idx = blockIdx.x * 256 + threadIdx.x;  // 256*256 threads
    int m = idx >> 8, kc = idx & 255;
    const float* src = h0 + (size_t)m * Hdim + kc * 8;
    int kb = kc >> 2, q = kc & 3;
    int lane = (m & 15) + 16 * q;
    int mt = m >> 4;
    f16x8 vh, vl;
    #pragma unroll
    for (int j = 0; j < 8; ++j) {
        float w = src[j];
        _Float16 h = (_Float16)w;
        vh[j] = h;
        vl[j] = (_Float16)(w - (float)h);
    }
    size_t off = (((size_t)mt * 64 + kb) * 64 + lane) * 8;
    *(f16x8*)(Ah + off) = vh;
    *(f16x8*)(Al + off) = vl;
}

// ---------------------------------------------------------------------------
// Kernel 1: hi/lo fp16 MFMA GEMM  C[256 x 6144] = A[256x2048] * W[6144x2048]^T
// C = Ah*Wh + Ah*Wl + Al*Wh  (fp32-equivalent precision)
// grid (128 N-tiles of 48, 4 K-slices of 512); 256 thr = 4 waves.
// B staged via global_load_lds (async DMA, 16B/lane); LDS 48 KB ->
// 3 wgs/CU -> 3 waves/SIMD. Wave w: rows [w*64,w*64+64) x 48 N (4x3 frags).
// ---------------------------------------------------------------------------
__global__ __launch_bounds__(256, 3)
void gemm_step(const _Float16* __restrict__ Ah, const _Float16* __restrict__ Al,
               const _Float16* __restrict__ Bh, const _Float16* __restrict__ Bl,
               float* __restrict__ Cpart) {
    // [buf][ hi: 12 blk x 64 lane x 8 | lo: same ]  (blk = ntl*4 + kbl)
    __shared__ __align__(16) _Float16 sB[2][12288];

    const int tid = threadIdx.x;
    const int wave = tid >> 6, lane = tid & 63;
    const int nt0 = blockIdx.x * 3;
    const int kb0 = blockIdx.y * 16;   // 16 kb-blocks (512 k) per slice

    f4 acc[4][3];
    #pragma unroll
    for (int mf = 0; mf < 4; ++mf)
        #pragma unroll
        for (int nf = 0; nf < 3; ++nf) acc[mf][nf] = (f4)0.f;

    // ---- async-stage chunk 0 into sB[0] ----
    #pragma unroll
    for (int i = 0; i < 3; ++i) {
        int blk = i * 4 + wave;            // wave-uniform
        int ntl = blk >> 2, kbl = blk & 3;
        size_t go = (((size_t)(nt0 + ntl) * 64) + kb0 + kbl) * 512 + lane * 8;
        int lb = (i * 256 + wave * 64) * 8;   // wave-uniform LDS base (halves)
        async16(Bh + go, &sB[0][lb]);
        async16(Bl + go, &sB[0][6144 + lb]);
    }
    __syncthreads();   // drains the DMA + barrier

    for (int c = 0; c < 4; ++c) {
        const int buf = c & 1;
        if (c < 3) {   // async-prefetch chunk c+1 into the other buffer
            #pragma unroll
            for (int i = 0; i < 3; ++i) {
                int blk = i * 4 + wave;
                int ntl = blk >> 2, kbl = blk & 3;
                size_t go = (((size_t)(nt0 + ntl) * 64) + kb0 + (c + 1) * 4 + kbl) * 512 + lane * 8;
                int lb = (i * 256 + wave * 64) * 8;
                async16(Bh + go, &sB[buf ^ 1][lb]);
                async16(Bl + go, &sB[buf ^ 1][6144 + lb]);
            }
        }
        #pragma unroll
        for (int kbl = 0; kbl < 4; ++kbl) {
            const int kb = kb0 + c * 4 + kbl;
            f16x8 a_h[4], a_l[4], b_h[3], b_l[3];
            #pragma unroll
            for (int mf = 0; mf < 4; ++mf) {
                size_t off = (((size_t)(wave * 4 + mf) * 64 + kb) * 64 + lane) * 8;
                a_h[mf] = *(const f16x8*)(Ah + off);
                a_l[mf] = *(const f16x8*)(Al + off);
            }
            #pragma unroll
            for (int nf = 0; nf < 3; ++nf) {
                int base = (nf * 4 + kbl) * 512 + lane * 8;
                b_h[nf] = *(const f16x8*)(&sB[buf][base]);
                b_l[nf] = *(const f16x8*)(&sB[buf][6144 + base]);
            }
            #pragma unroll
            for (int mf = 0; mf < 4; ++mf)
                #pragma unroll
                for (int nf = 0; nf < 3; ++nf) {
                    acc[mf][nf] = __builtin_amdgcn_mfma_f32_16x16x32_f16(
                        a_h[mf], b_h[nf], acc[mf][nf], 0, 0, 0);
                    acc[mf][nf] = __builtin_amdgcn_mfma_f32_16x16x32_f16(
                        a_h[mf], b_l[nf], acc[mf][nf], 0, 0, 0);
                    acc[mf][nf] = __builtin_amdgcn_mfma_f32_16x16x32_f16(
                        a_l[mf], b_h[nf], acc[mf][nf], 0, 0, 0);
                }
        }
        if (c < 3) __syncthreads();   // drains prefetch DMA + releases buf
    }

    // store partials: C/D frag: col(N)=lane&15, row(M)=(lane>>4)*4+q
    const size_t base = (size_t)blockIdx.y * 256 * G3;
    #pragma unroll
    for (int mf = 0; mf < 4; ++mf) {
        int mrow = wave * 64 + mf * 16 + (lane >> 4) * 4;
        #pragma unroll
        for (int nf = 0; nf < 3; ++nf) {
            int n = (nt0 + nf) * 16 + (lane & 15);
            #pragma unroll
            for (int q = 0; q < 4; ++q)
                Cpart[base + (size_t)(mrow + q) * G3 + n] = acc[mf][nf][q];
        }
    }
}

// ---------------------------------------------------------------------------
// Kernel 2: fused epilogue. grid 256 (wg = batch row b), 256 thr.
// Sums 4 K-partials + b_hh + gi (table via topi/alive), gates, writes h fp32
// + hi/lo fp16 A-pack, then logits/argmax/log_softmax/topi (+h_final).
// ---------------------------------------------------------------------------
__global__ __launch_bounds__(256)
void fused_out(const float* __restrict__ hprev, float* __restrict__ hnew,
               const float* __restrict__ Cpart, const float* __restrict__ Gt,
               const float* __restrict__ gi0, const float* __restrict__ b_hh,
               const float* __restrict__ W_out, const float* __restrict__ b_out,
               _Float16* __restrict__ Ah, _Float16* __restrict__ Al,
               const int* __restrict__ topi_in, int* __restrict__ topi_out,
               float* __restrict__ lp, float* __restrict__ hfin, int t) {
    const int b = blockIdx.x;
    const int tid = threadIdx.x;
    __shared__ __align__(16) float sh[Hdim];
    __shared__ float sl[16];
    __shared__ int s_sel;
    __shared__ unsigned long long s_m[4];

    if (t > 0) {
        int tp = topi_in[tid];
        unsigned long long m = __ballot(tp == (Odim - 1));
        if ((tid & 63) == 0) s_m[tid >> 6] = m;
        __syncthreads();
        if (tid == 0) {
            int bw = b >> 6, bl = b & 63;
            unsigned long long le =
                s_m[bw] & ((bl == 63) ? ~0ULL : ((1ULL << (bl + 1)) - 1ULL));
            bool dead = (le != 0ULL);
            for (int w = 0; w < bw; ++w) dead = dead || (s_m[w] != 0ULL);
            s_sel = dead ? Odim : topi_in[b];
        }
        __syncthreads();
    }
    const float* gp = (t == 0) ? (gi0 + (size_t)b * G3)
                               : (Gt + (size_t)s_sel * G3);

    const int j0 = tid * 8;
    float hn[8];
    {
        float gsum[3][8];
        #pragma unroll
        for (int g = 0; g < 3; ++g) {
            f4 s0 = *(const f4*)(b_hh + g * Hdim + j0);
            f4 s1 = *(const f4*)(b_hh + g * Hdim + j0 + 4);
            #pragma unroll
            for (int c = 0; c < 4; ++c) { gsum[g][c] = s0[c]; gsum[g][4 + c] = s1[c]; }
            #pragma unroll
            for (int ks = 0; ks < 4; ++ks) {
                const float* cp = Cpart + ((size_t)ks * Bdim + b) * G3 + g * Hdim + j0;
                f4 p0 = *(const f4*)cp;
                f4 p1 = *(const f4*)(cp + 4);
                #pragma unroll
                for (int c = 0; c < 4; ++c) { gsum[g][c] += p0[c]; gsum[g][4 + c] += p1[c]; }
            }
        }
        f4 hp0 = *(const f4*)(hprev + (size_t)b * Hdim + j0);
        f4 hp1 = *(const f4*)(hprev + (size_t)b * Hdim + j0 + 4);
        f4 gr0 = *(const f4*)(gp + j0),            gr1 = *(const f4*)(gp + j0 + 4);
        f4 gz0 = *(const f4*)(gp + Hdim + j0),     gz1 = *(const f4*)(gp + Hdim + j0 + 4);
        f4 gn0 = *(const f4*)(gp + 2 * Hdim + j0), gn1 = *(const f4*)(gp + 2 * Hdim + j0 + 4);
        #pragma unroll
        for (int c = 0; c < 8; ++c) {
            float gi_r = (c < 4) ? gr0[c] : gr1[c - 4];
            float gi_z = (c < 4) ? gz0[c] : gz1[c - 4];
            float gi_n = (c < 4) ? gn0[c] : gn1[c - 4];
            float hp   = (c < 4) ? hp0[c] : hp1[c - 4];
            float rr = 1.f / (1.f + expf(-(gi_r + gsum[0][c])));
            float zz = 1.f / (1.f + expf(-(gi_z + gsum[1][c])));
            float nn = tanhf(fmaf(rr, gsum[2][c], gi_n));
            hn[c] = (1.f - zz) * nn + zz * hp;
        }
    }
    f4 o0, o1;
    #pragma unroll
    for (int c = 0; c < 4; ++c) { o0[c] = hn[c]; o1[c] = hn[4 + c]; }
    *(f4*)(hnew + (size_t)b * Hdim + j0) = o0;
    *(f4*)(hnew + (size_t)b * Hdim + j0 + 4) = o1;
    {   // hi/lo fp16 A-pack: mt=b>>4, kb=tid>>2, q=tid&3, lane=(b&15)+16q
        f16x8 vh, vl;
        #pragma unroll
        for (int c = 0; c < 8; ++c) {
            _Float16 hh = (_Float16)hn[c];
            vh[c] = hh;
            vl[c] = (_Float16)(hn[c] - (float)hh);
        }
        int kb = tid >> 2, q = tid & 3;
        int lane = (b & 15) + 16 * q, mt = b >> 4;
        size_t off = (((size_t)mt * 64 + kb) * 64 + lane) * 8;
        *(f16x8*)(Ah + off) = vh;
        *(f16x8*)(Al + off) = vl;
    }
    *(f4*)(sh + j0) = o0;
    *(f4*)(sh + j0 + 4) = o1;
    __syncthreads();

    const int w = tid >> 6, l = tid & 63;
    for (int o = w; o < Odim; o += 4) {
        const float* wo = W_out + (size_t)o * Hdim;
        float s = 0.f;
        #pragma unroll
        for (int i = 0; i < 32; ++i)
            s = fmaf(sh[l + 64 * i], wo[l + 64 * i], s);
        #pragma unroll
        for (int off = 32; off >= 1; off >>= 1)
            s += __shfl_down(s, off);
        if (l == 0) sl[o] = s + b_out[o];
    }
    __syncthreads();
    if (tid == 0) {
        float m = sl[0]; int bi = 0;
        #pragma unroll
        for (int o = 1; o < Odim; ++o)
            if (sl[o] > m) { m = sl[o]; bi = o; }   // strict > = first max
        float ssum = 0.f;
        #pragma unroll
        for (int o = 0; o < Odim; ++o) ssum += expf(sl[o] - m);
        topi_out[b] = bi;
        sl[14] = m + logf(ssum);
    }
    __syncthreads();
    if (tid < Odim)
        lp[(size_t)b * (Tdim * Odim) + (size_t)t * Odim + tid] = sl[tid] - sl[14];
    if (hfin) {
        *(f4*)(hfin + (size_t)b * Hdim + j0) = o0;
        *(f4*)(hfin + (size_t)b * Hdim + j0 + 4) = o1;
    }
}

// ---------------------------------------------------------------------------
extern "C" void kernel_launch(void* const* d_in, const int* in_sizes, int n_in,
                              void* d_out, int out_size, void* d_ws, size_t ws_size,
                              hipStream_t stream) {
    const float* enc_hidden = (const float*)d_in[1];
    const float* target     = (const float*)d_in[2];
    const float* W_ih       = (const float*)d_in[3];
    const float* W_hh       = (const float*)d_in[4];
    const float* b_ih       = (const float*)d_in[5];
    const float* b_hh       = (const float*)d_in[6];
    const float* W_out      = (const float*)d_in[7];
    const float* b_out      = (const float*)d_in[8];

    float* out  = (float*)d_out;
    float* lp   = out;
    float* hfin = out + (size_t)Bdim * Tdim * Odim;

    float* ws    = (float*)d_ws;
    float* hb0   = ws;                        // 524288
    float* hb1   = hb0 + 524288;              // 524288
    float* Gt    = hb1 + 524288;              // 92160
    float* gi0   = Gt + 15 * G3;              // 1572864
    float* Cpart = gi0 + (size_t)Bdim * G3;   // 4*1572864
    _Float16* Ah = (_Float16*)(Cpart + 4 * (size_t)Bdim * G3);  // 524288 halves
    _Float16* Al = Ah + (size_t)Bdim * Hdim;                    // 524288
    _Float16* Bh = Al + (size_t)Bdim * Hdim;                    // 12582912
    _Float16* Bl = Bh + (size_t)G3 * Hdim;                      // 12582912
    int* topibuf = (int*)(Bl + (size_t)G3 * Hdim);              // 512 ints

    prep_gtable<<<(15 * G3 + 255) / 256, 256, 0, stream>>>(b_ih, W_ih, Gt);
    prep_gi0<<<(Bdim * G3) / 256, 256, 0, stream>>>(b_ih, W_ih, target, gi0);
    prep_Bpack<<<(G3 * 256) / 256, 256, 0, stream>>>(W_hh, Bh, Bl);
    prep_A0<<<(Bdim * 256) / 256, 256, 0, stream>>>(enc_hidden, Ah, Al);

    for (int t = 0; t < Tdim; ++t) {
        float* hnew = (t & 1) ? hb1 : hb0;
        const float* hprev = (t == 0) ? enc_hidden : ((t & 1) ? hb0 : hb1);
        int* tin  = topibuf + ((t + 1) & 1) * 256;
        int* tout = topibuf + (t & 1) * 256;
        gemm_step<<<dim3(128, 4), 256, 0, stream>>>(Ah, Al, Bh, Bl, Cpart);
        fused_out<<<256, 256, 0, stream>>>(hprev, hnew, Cpart, Gt, gi0, b_hh,
                                           W_out, b_out, Ah, Al, tin, tout, lp,
                                           (t == Tdim - 1) ? hfin : nullptr, t);
    }
}

// Round 8
// 19928.691 us; speedup vs baseline: 1.0241x; 1.0241x over previous
//
#include <hip/hip_runtime.h>
#include <math.h>

typedef float f4 __attribute__((ext_vector_type(4)));
typedef _Float16 f16x8 __attribute__((ext_vector_type(8)));
typedef int i4 __attribute__((ext_vector_type(4)));

#define Hdim 2048
#define Bdim 256
#define Tdim 512
#define Odim 14
#define G3   6144   // 3*Hdim

// ---------------------------------------------------------------------------
// Prep kernels (once per launch)
// ---------------------------------------------------------------------------

__global__ void prep_gtable(const float* __restrict__ b_ih,
                            const float* __restrict__ W_ih,
                            float* __restrict__ Gt) {
    int idx = blockIdx.x * 256 + threadIdx.x;
    if (idx >= 15 * G3) return;
    int c = idx / G3, row = idx % G3;
    float v = b_ih[row];
    if (c < Odim) v += W_ih[row * Odim + c];
    Gt[idx] = v;
}

__global__ void prep_gi0(const float* __restrict__ b_ih,
                         const float* __restrict__ W_ih,
                         const float* __restrict__ target,
                         float* __restrict__ gi0) {
    int idx = blockIdx.x * 256 + threadIdx.x;
    int b = idx / G3, row = idx % G3;
    const float* x0 = target + (size_t)b * (Tdim * Odim);
    float s = b_ih[row];
    #pragma unroll
    for (int c = 0; c < Odim; ++c)
        s = fmaf(fmaxf(x0[c], 0.f), W_ih[row * Odim + c], s);
    gi0[idx] = s;
}

// W_hh (6144x2048 f32) -> hi/lo fp16 frag-major: [nt][kb][lane][8]
// n = nt*16 + (lane&15), k = kb*32 + (lane>>4)*8 + j
__global__ void prep_Bpack(const float* __restrict__ W,
                           _Float16* __restrict__ Bh, _Float16* __restrict__ Bl) {
    int idx = blockIdx.x * 256 + threadIdx.x;  // 6144*256 threads
    int n = idx >> 8, kc = idx & 255;
    const float* src = W + (size_t)n * Hdim + kc * 8;
    int kb = kc >> 2, q = kc & 3;
    int lane = (n & 15) + 16 * q;
    int nt = n >> 4;
    f16x8 vh, vl;
    #pragma unroll
    for (int j = 0; j < 8; ++j) {
        float w = src[j];
        _Float16 h = (_Float16)w;
        vh[j] = h;
        vl[j] = (_Float16)(w - (float)h);
    }
    size_t off = (((size_t)nt * 64 + kb) * 64 + lane) * 8;
    *(f16x8*)(Bh + off) = vh;
    *(f16x8*)(Bl + off) = vl;
}

// enc_hidden (256x2048 f32) -> hi/lo fp16 frag-major: [mt][kb][lane][8]
__global__ void prep_A0(const float* __restrict__ h0,
                        _Float16* __restrict__ Ah, _Float16* __restrict__ Al) {
    int idx = blockIdx.x * 256 + threadIdx.x;  // 256*256 threads
    int m = idx >> 8, kc = idx & 255;
    const float* src = h0 + (size_t)m * Hdim + kc * 8;
    int kb = kc >> 2, q = kc & 3;
    int lane = (m & 15) + 16 * q;
    int mt = m >> 4;
    f16x8 vh, vl;
    #pragma unroll
    for (int j = 0; j < 8; ++j) {
        float w = src[j];
        _Float16 h = (_Float16)w;
        vh[j] = h;
        vl[j] = (_Float16)(w - (float)h);
    }
    size_t off = (((size_t)mt * 64 + kb) * 64 + lane) * 8;
    *(f16x8*)(Ah + off) = vh;
    *(f16x8*)(Al + off) = vl;
}

// ---------------------------------------------------------------------------
// Kernel 1: hi/lo fp16 MFMA GEMM  C[256 x 6144] = A[256x2048] * W[6144x2048]^T
// C = Ah*Wh + Ah*Wl + Al*Wh  (fp32-equivalent precision)
// grid (64 N-tiles of 96, 4 K-slices of 512); 512 thr = 8 waves (1 wg/CU,
// 2 waves/SIMD). Wave w: rows [w*32, w*32+32) x all 96 N (mf=2 x nf=6).
// A-traffic halved vs 48-wide tiles: each A element read by 64 wgs, not 128.
// ---------------------------------------------------------------------------
__global__ __launch_bounds__(512, 1)
void gemm_step(const _Float16* __restrict__ Ah, const _Float16* __restrict__ Al,
               const _Float16* __restrict__ Bh, const _Float16* __restrict__ Bl,
               float* __restrict__ Cpart) {
    // [buf][ hi: 24 blk x 64 lane x 8 | lo: same ]  (blk = ntl*4 + kbl)
    __shared__ __align__(16) _Float16 sB[2][24576];   // 96 KB total

    const int tid = threadIdx.x;
    const int wave = tid >> 6, lane = tid & 63;
    const int nt0 = blockIdx.x * 6;    // 6 frag-rows of 16 = 96 N
    const int kb0 = blockIdx.y * 16;   // 16 kb-blocks (512 k) per slice

    f4 acc[2][6];
    #pragma unroll
    for (int mf = 0; mf < 2; ++mf)
        #pragma unroll
        for (int nf = 0; nf < 6; ++nf) acc[mf][nf] = (f4)0.f;

    i4 rh[3], rl[3];

    // stage chunk 0 (4 kb-blocks x 6 frag-rows, hi+lo)
    #pragma unroll
    for (int i = 0; i < 3; ++i) {
        int e = i * 512 + tid, blk = e >> 6, l = e & 63;
        int ntl = blk >> 2, kbl = blk & 3;
        size_t off = (((size_t)(nt0 + ntl) * 64) + kb0 + kbl) * 512 + l * 8;
        rh[i] = *(const i4*)(Bh + off);
        rl[i] = *(const i4*)(Bl + off);
    }
    #pragma unroll
    for (int i = 0; i < 3; ++i) {
        ((i4*)sB[0])[i * 512 + tid] = rh[i];
        ((i4*)sB[0])[1536 + i * 512 + tid] = rl[i];
    }
    __syncthreads();

    for (int c = 0; c < 4; ++c) {
        const int buf = c & 1;
        if (c < 3) {  // register-prefetch chunk c+1
            #pragma unroll
            for (int i = 0; i < 3; ++i) {
                int e = i * 512 + tid, blk = e >> 6, l = e & 63;
                int ntl = blk >> 2, kbl = blk & 3;
                size_t off = (((size_t)(nt0 + ntl) * 64) + kb0 + (c + 1) * 4 + kbl) * 512 + l * 8;
                rh[i] = *(const i4*)(Bh + off);
                rl[i] = *(const i4*)(Bl + off);
            }
        }
        #pragma unroll
        for (int kbl = 0; kbl < 4; ++kbl) {
            const int kb = kb0 + c * 4 + kbl;
            f16x8 a_h[2], a_l[2], b_h[6], b_l[6];
            #pragma unroll
            for (int mf = 0; mf < 2; ++mf) {
                size_t off = (((size_t)(wave * 2 + mf) * 64 + kb) * 64 + lane) * 8;
                a_h[mf] = *(const f16x8*)(Ah + off);
                a_l[mf] = *(const f16x8*)(Al + off);
            }
            #pragma unroll
            for (int nf = 0; nf < 6; ++nf) {
                int base = (nf * 4 + kbl) * 512 + lane * 8;
                b_h[nf] = *(const f16x8*)(&sB[buf][base]);
                b_l[nf] = *(const f16x8*)(&sB[buf][12288 + base]);
            }
            #pragma unroll
            for (int mf = 0; mf < 2; ++mf)
                #pragma unroll
                for (int nf = 0; nf < 6; ++nf) {
                    acc[mf][nf] = __builtin_amdgcn_mfma_f32_16x16x32_f16(
                        a_h[mf], b_h[nf], acc[mf][nf], 0, 0, 0);
                    acc[mf][nf] = __builtin_amdgcn_mfma_f32_16x16x32_f16(
                        a_h[mf], b_l[nf], acc[mf][nf], 0, 0, 0);
                    acc[mf][nf] = __builtin_amdgcn_mfma_f32_16x16x32_f16(
                        a_l[mf], b_h[nf], acc[mf][nf], 0, 0, 0);
                }
        }
        if (c < 3) {  // store prefetched chunk into the other buffer
            __syncthreads();
            #pragma unroll
            for (int i = 0; i < 3; ++i) {
                ((i4*)sB[buf ^ 1])[i * 512 + tid] = rh[i];
                ((i4*)sB[buf ^ 1])[1536 + i * 512 + tid] = rl[i];
            }
            __syncthreads();
        }
    }

    // store partials: C/D frag: col(N)=lane&15, row(M)=(lane>>4)*4+q
    const size_t base = (size_t)blockIdx.y * 256 * G3;
    #pragma unroll
    for (int mf = 0; mf < 2; ++mf) {
        int mrow = wave * 32 + mf * 16 + (lane >> 4) * 4;
        #pragma unroll
        for (int nf = 0; nf < 6; ++nf) {
            int n = (nt0 + nf) * 16 + (lane & 15);
            #pragma unroll
            for (int q = 0; q < 4; ++q)
                Cpart[base + (size_t)(mrow + q) * G3 + n] = acc[mf][nf][q];
        }
    }
}

// ---------------------------------------------------------------------------
// Kernel 2: fused epilogue. grid 256 (wg = batch row b), 256 thr.
// Sums 4 K-partials + b_hh + gi (table via topi/alive), gates, writes h fp32
// + hi/lo fp16 A-pack, then logits/argmax/log_softmax/topi (+h_final).
// ---------------------------------------------------------------------------
__global__ __launch_bounds__(256)
void fused_out(const float* __restrict__ hprev, float* __restrict__ hnew,
               const float* __restrict__ Cpart, const float* __restrict__ Gt,
               const float* __restrict__ gi0, const float* __restrict__ b_hh,
               const float* __restrict__ W_out, const float* __restrict__ b_out,
               _Float16* __restrict__ Ah, _Float16* __restrict__ Al,
               const int* __restrict__ topi_in, int* __restrict__ topi_out,
               float* __restrict__ lp, float* __restrict__ hfin, int t) {
    const int b = blockIdx.x;
    const int tid = threadIdx.x;
    __shared__ __align__(16) float sh[Hdim];
    __shared__ float sl[16];
    __shared__ int s_sel;
    __shared__ unsigned long long s_m[4];

    if (t > 0) {
        int tp = topi_in[tid];
        unsigned long long m = __ballot(tp == (Odim - 1));
        if ((tid & 63) == 0) s_m[tid >> 6] = m;
        __syncthreads();
        if (tid == 0) {
            int bw = b >> 6, bl = b & 63;
            unsigned long long le =
                s_m[bw] & ((bl == 63) ? ~0ULL : ((1ULL << (bl + 1)) - 1ULL));
            bool dead = (le != 0ULL);
            for (int w = 0; w < bw; ++w) dead = dead || (s_m[w] != 0ULL);
            s_sel = dead ? Odim : topi_in[b];
        }
        __syncthreads();
    }
    const float* gp = (t == 0) ? (gi0 + (size_t)b * G3)
                               : (Gt + (size_t)s_sel * G3);

    const int j0 = tid * 8;
    float hn[8];
    {
        float gsum[3][8];
        #pragma unroll
        for (int g = 0; g < 3; ++g) {
            f4 s0 = *(const f4*)(b_hh + g * Hdim + j0);
            f4 s1 = *(const f4*)(b_hh + g * Hdim + j0 + 4);
            #pragma unroll
            for (int c = 0; c < 4; ++c) { gsum[g][c] = s0[c]; gsum[g][4 + c] = s1[c]; }
            #pragma unroll
            for (int ks = 0; ks < 4; ++ks) {
                const float* cp = Cpart + ((size_t)ks * Bdim + b) * G3 + g * Hdim + j0;
                f4 p0 = *(const f4*)cp;
                f4 p1 = *(const f4*)(cp + 4);
                #pragma unroll
                for (int c = 0; c < 4; ++c) { gsum[g][c] += p0[c]; gsum[g][4 + c] += p1[c]; }
            }
        }
        f4 hp0 = *(const f4*)(hprev + (size_t)b * Hdim + j0);
        f4 hp1 = *(const f4*)(hprev + (size_t)b * Hdim + j0 + 4);
        f4 gr0 = *(const f4*)(gp + j0),            gr1 = *(const f4*)(gp + j0 + 4);
        f4 gz0 = *(const f4*)(gp + Hdim + j0),     gz1 = *(const f4*)(gp + Hdim + j0 + 4);
        f4 gn0 = *(const f4*)(gp + 2 * Hdim + j0), gn1 = *(const f4*)(gp + 2 * Hdim + j0 + 4);
        #pragma unroll
        for (int c = 0; c < 8; ++c) {
            float gi_r = (c < 4) ? gr0[c] : gr1[c - 4];
            float gi_z = (c < 4) ? gz0[c] : gz1[c - 4];
            float gi_n = (c < 4) ? gn0[c] : gn1[c - 4];
            float hp   = (c < 4) ? hp0[c] : hp1[c - 4];
            float rr = 1.f / (1.f + expf(-(gi_r + gsum[0][c])));
            float zz = 1.f / (1.f + expf(-(gi_z + gsum[1][c])));
            float nn = tanhf(fmaf(rr, gsum[2][c], gi_n));
            hn[c] = (1.f - zz) * nn + zz * hp;
        }
    }
    f4 o0, o1;
    #pragma unroll
    for (int c = 0; c < 4; ++c) { o0[c] = hn[c]; o1[c] = hn[4 + c]; }
    *(f4*)(hnew + (size_t)b * Hdim + j0) = o0;
    *(f4*)(hnew + (size_t)b * Hdim + j0 + 4) = o1;
    {   // hi/lo fp16 A-pack: mt=b>>4, kb=tid>>2, q=tid&3, lane=(b&15)+16q
        f16x8 vh, vl;
        #pragma unroll
        for (int c = 0; c < 8; ++c) {
            _Float16 hh = (_Float16)hn[c];
            vh[c] = hh;
            vl[c] = (_Float16)(hn[c] - (float)hh);
        }
        int kb = tid >> 2, q = tid & 3;
        int lane = (b & 15) + 16 * q, mt = b >> 4;
        size_t off = (((size_t)mt * 64 + kb) * 64 + lane) * 8;
        *(f16x8*)(Ah + off) = vh;
        *(f16x8*)(Al + off) = vl;
    }
    *(f4*)(sh + j0) = o0;
    *(f4*)(sh + j0 + 4) = o1;
    __syncthreads();

    const int w = tid >> 6, l = tid & 63;
    for (int o = w; o < Odim; o += 4) {
        const float* wo = W_out + (size_t)o * Hdim;
        float s = 0.f;
        #pragma unroll
        for (int i = 0; i < 32; ++i)
            s = fmaf(sh[l + 64 * i], wo[l + 64 * i], s);
        #pragma unroll
        for (int off = 32; off >= 1; off >>= 1)
            s += __shfl_down(s, off);
        if (l == 0) sl[o] = s + b_out[o];
    }
    __syncthreads();
    if (tid == 0) {
        float m = sl[0]; int bi = 0;
        #pragma unroll
        for (int o = 1; o < Odim; ++o)
            if (sl[o] > m) { m = sl[o]; bi = o; }   // strict > = first max
        float ssum = 0.f;
        #pragma unroll
        for (int o = 0; o < Odim; ++o) ssum += expf(sl[o] - m);
        topi_out[b] = bi;
        sl[14] = m + logf(ssum);
    }
    __syncthreads();
    if (tid < Odim)
        lp[(size_t)b * (Tdim * Odim) + (size_t)t * Odim + tid] = sl[tid] - sl[14];
    if (hfin) {
        *(f4*)(hfin + (size_t)b * Hdim + j0) = o0;
        *(f4*)(hfin + (size_t)b * Hdim + j0 + 4) = o1;
    }
}

// ---------------------------------------------------------------------------
extern "C" void kernel_launch(void* const* d_in, const int* in_sizes, int n_in,
                              void* d_out, int out_size, void* d_ws, size_t ws_size,
                              hipStream_t stream) {
    const float* enc_hidden = (const float*)d_in[1];
    const float* target     = (const float*)d_in[2];
    const float* W_ih       = (const float*)d_in[3];
    const float* W_hh       = (const float*)d_in[4];
    const float* b_ih       = (const float*)d_in[5];
    const float* b_hh       = (const float*)d_in[6];
    const float* W_out      = (const float*)d_in[7];
    const float* b_out      = (const float*)d_in[8];

    float* out  = (float*)d_out;
    float* lp   = out;
    float* hfin = out + (size_t)Bdim * Tdim * Odim;

    float* ws    = (float*)d_ws;
    float* hb0   = ws;                        // 524288
    float* hb1   = hb0 + 524288;              // 524288
    float* Gt    = hb1 + 524288;              // 92160
    float* gi0   = Gt + 15 * G3;              // 1572864
    float* Cpart = gi0 + (size_t)Bdim * G3;   // 4*1572864
    _Float16* Ah = (_Float16*)(Cpart + 4 * (size_t)Bdim * G3);  // 524288 halves
    _Float16* Al = Ah + (size_t)Bdim * Hdim;                    // 524288
    _Float16* Bh = Al + (size_t)Bdim * Hdim;                    // 12582912
    _Float16* Bl = Bh + (size_t)G3 * Hdim;                      // 12582912
    int* topibuf = (int*)(Bl + (size_t)G3 * Hdim);              // 512 ints

    prep_gtable<<<(15 * G3 + 255) / 256, 256, 0, stream>>>(b_ih, W_ih, Gt);
    prep_gi0<<<(Bdim * G3) / 256, 256, 0, stream>>>(b_ih, W_ih, target, gi0);
    prep_Bpack<<<(G3 * 256) / 256, 256, 0, stream>>>(W_hh, Bh, Bl);
    prep_A0<<<(Bdim * 256) / 256, 256, 0, stream>>>(enc_hidden, Ah, Al);

    for (int t = 0; t < Tdim; ++t) {
        float* hnew = (t & 1) ? hb1 : hb0;
        const float* hprev = (t == 0) ? enc_hidden : ((t & 1) ? hb0 : hb1);
        int* tin  = topibuf + ((t + 1) & 1) * 256;
        int* tout = topibuf + (t & 1) * 256;
        gemm_step<<<dim3(64, 4), 512, 0, stream>>>(Ah, Al, Bh, Bl, Cpart);
        fused_out<<<256, 256, 0, stream>>>(hprev, hnew, Cpart, Gt, gi0, b_hh,
                                           W_out, b_out, Ah, Al, tin, tout, lp,
                                           (t == Tdim - 1) ? hfin : nullptr, t);
    }
}

// Round 10
// 19320.580 us; speedup vs baseline: 1.0564x; 1.0315x over previous
//
#include <hip/hip_runtime.h>
#include <math.h>

typedef float f4 __attribute__((ext_vector_type(4)));
typedef _Float16 f16x8 __attribute__((ext_vector_type(8)));
typedef _Float16 f16x4 __attribute__((ext_vector_type(4)));
typedef int i4 __attribute__((ext_vector_type(4)));

#define Hdim 2048
#define Bdim 256
#define Tdim 512
#define Odim 14
#define G3   6144   // 3*Hdim

// ---------------------------------------------------------------------------
// Prep kernels (once per launch)
// ---------------------------------------------------------------------------

__global__ void prep_gtable(const float* __restrict__ b_ih,
                            const float* __restrict__ W_ih,
                            float* __restrict__ Gt) {
    int idx = blockIdx.x * 256 + threadIdx.x;
    if (idx >= 15 * G3) return;
    int c = idx / G3, row = idx % G3;
    float v = b_ih[row];
    if (c < Odim) v += W_ih[row * Odim + c];
    Gt[idx] = v;
}

__global__ void prep_gi0(const float* __restrict__ b_ih,
                         const float* __restrict__ W_ih,
                         const float* __restrict__ target,
                         float* __restrict__ gi0) {
    int idx = blockIdx.x * 256 + threadIdx.x;
    int b = idx / G3, row = idx % G3;
    const float* x0 = target + (size_t)b * (Tdim * Odim);
    float s = b_ih[row];
    #pragma unroll
    for (int c = 0; c < Odim; ++c)
        s = fmaf(fmaxf(x0[c], 0.f), W_ih[row * Odim + c], s);
    gi0[idx] = s;
}

// W_hh (6144x2048 f32) -> hi/lo fp16 frag-major: [nt][kb][lane][8]
// n = nt*16 + (lane&15), k = kb*32 + (lane>>4)*8 + j
__global__ void prep_Bpack(const float* __restrict__ W,
                           _Float16* __restrict__ Bh, _Float16* __restrict__ Bl) {
    int idx = blockIdx.x * 256 + threadIdx.x;  // 6144*256 threads
    int n = idx >> 8, kc = idx & 255;
    const float* src = W + (size_t)n * Hdim + kc * 8;
    int kb = kc >> 2, q = kc & 3;
    int lane = (n & 15) + 16 * q;
    int nt = n >> 4;
    f16x8 vh, vl;
    #pragma unroll
    for (int j = 0; j < 8; ++j) {
        float w = src[j];
        _Float16 h = (_Float16)w;
        vh[j] = h;
        vl[j] = (_Float16)(w - (float)h);
    }
    size_t off = (((size_t)nt * 64 + kb) * 64 + lane) * 8;
    *(f16x8*)(Bh + off) = vh;
    *(f16x8*)(Bl + off) = vl;
}

// enc_hidden (256x2048 f32) -> hi/lo fp16 frag-major: [mt][kb][lane][8]
__global__ void prep_A0(const float* __restrict__ h0,
                        _Float16* __restrict__ Ah, _Float16* __restrict__ Al) {
    int idx = blockIdx.x * 256 + threadIdx.x;  // 256*256 threads
    int m = idx >> 8, kc = idx & 255;
    const float* src = h0 + (size_t)m * Hdim + kc * 8;
    int kb = kc >> 2, q = kc & 3;
    int lane = (m & 15) + 16 * q;
    int mt = m >> 4;
    f16x8 vh, vl;
    #pragma unroll
    for (int j = 0; j < 8; ++j) {
        float w = src[j];
        _Float16 h = (_Float16)w;
        vh[j] = h;
        vl[j] = (_Float16)(w - (float)h);
    }
    size_t off = (((size_t)mt * 64 + kb) * 64 + lane) * 8;
    *(f16x8*)(Ah + off) = vh;
    *(f16x8*)(Al + off) = vl;
}

// ---------------------------------------------------------------------------
// Kernel 1: hi/lo fp16 MFMA GEMM  C[256 x 6144] = A[256x2048] * W[6144x2048]^T
// C = Ah*Wh + Ah*Wl + Al*Wh  (fp32-equivalent precision)
// grid (128 N-tiles of 48, 2 K-slices of 1024); 512 thr = 8 waves (1 wg/CU,
// 2 waves/SIMD). Wave w: rows [w*32, w*32+32) x 48 N (mf=2 x nf=3).
// K-chunks of 256 (8 kb-blocks), double-buffered, register-prefetch.
// Split-K=2: Cpart traffic halved vs split-K=4.
// ---------------------------------------------------------------------------
__global__ __launch_bounds__(512, 2)
void gemm_step(const _Float16* __restrict__ Ah, const _Float16* __restrict__ Al,
               const _Float16* __restrict__ Bh, const _Float16* __restrict__ Bl,
               float* __restrict__ Cpart) {
    // [buf][ hi: 24 blk x 64 lane x 8 | lo: same ]  (blk = ntl*8 + kbl)
    __shared__ __align__(16) _Float16 sB[2][24576];   // 96 KB total

    const int tid = threadIdx.x;
    const int wave = tid >> 6, lane = tid & 63;
    const int nt0 = blockIdx.x * 3;    // 3 frag-rows of 16 = 48 N
    const int kb0 = blockIdx.y * 32;   // 32 kb-blocks (1024 k) per slice

    f4 acc[2][3];
    #pragma unroll
    for (int mf = 0; mf < 2; ++mf)
        #pragma unroll
        for (int nf = 0; nf < 3; ++nf) acc[mf][nf] = (f4)0.f;

    i4 rh[3], rl[3];

    // stage chunk 0 (8 kb-blocks x 3 frag-rows, hi+lo)
    #pragma unroll
    for (int i = 0; i < 3; ++i) {
        int e = i * 512 + tid, blk = e >> 6, l = e & 63;
        int ntl = blk >> 3, kbl = blk & 7;
        size_t off = (((size_t)(nt0 + ntl) * 64) + kb0 + kbl) * 512 + l * 8;
        rh[i] = *(const i4*)(Bh + off);
        rl[i] = *(const i4*)(Bl + off);
    }
    #pragma unroll
    for (int i = 0; i < 3; ++i) {
        ((i4*)sB[0])[i * 512 + tid] = rh[i];
        ((i4*)sB[0])[1536 + i * 512 + tid] = rl[i];
    }
    __syncthreads();

    for (int c = 0; c < 4; ++c) {
        const int buf = c & 1;
        if (c < 3) {  // register-prefetch chunk c+1
            #pragma unroll
            for (int i = 0; i < 3; ++i) {
                int e = i * 512 + tid, blk = e >> 6, l = e & 63;
                int ntl = blk >> 3, kbl = blk & 7;
                size_t off = (((size_t)(nt0 + ntl) * 64) + kb0 + (c + 1) * 8 + kbl) * 512 + l * 8;
                rh[i] = *(const i4*)(Bh + off);
                rl[i] = *(const i4*)(Bl + off);
            }
        }
        #pragma unroll
        for (int kbl = 0; kbl < 8; ++kbl) {
            const int kb = kb0 + c * 8 + kbl;
            f16x8 a_h[2], a_l[2], b_h[3], b_l[3];
            #pragma unroll
            for (int mf = 0; mf < 2; ++mf) {
                size_t off = (((size_t)(wave * 2 + mf) * 64 + kb) * 64 + lane) * 8;
                a_h[mf] = *(const f16x8*)(Ah + off);
                a_l[mf] = *(const f16x8*)(Al + off);
            }
            #pragma unroll
            for (int nf = 0; nf < 3; ++nf) {
                int base = ((nf * 8 + kbl) * 64 + lane) * 8;
                b_h[nf] = *(const f16x8*)(&sB[buf][base]);
                b_l[nf] = *(const f16x8*)(&sB[buf][12288 + base]);
            }
            #pragma unroll
            for (int mf = 0; mf < 2; ++mf)
                #pragma unroll
                for (int nf = 0; nf < 3; ++nf) {
                    acc[mf][nf] = __builtin_amdgcn_mfma_f32_16x16x32_f16(
                        a_h[mf], b_h[nf], acc[mf][nf], 0, 0, 0);
                    acc[mf][nf] = __builtin_amdgcn_mfma_f32_16x16x32_f16(
                        a_h[mf], b_l[nf], acc[mf][nf], 0, 0, 0);
                    acc[mf][nf] = __builtin_amdgcn_mfma_f32_16x16x32_f16(
                        a_l[mf], b_h[nf], acc[mf][nf], 0, 0, 0);
                }
        }
        if (c < 3) {  // store prefetched chunk into the other buffer
            __syncthreads();
            #pragma unroll
            for (int i = 0; i < 3; ++i) {
                ((i4*)sB[buf ^ 1])[i * 512 + tid] = rh[i];
                ((i4*)sB[buf ^ 1])[1536 + i * 512 + tid] = rl[i];
            }
            __syncthreads();
        }
    }

    // store partials: C/D frag: col(N)=lane&15, row(M)=(lane>>4)*4+q
    const size_t base = (size_t)blockIdx.y * Bdim * G3;
    #pragma unroll
    for (int mf = 0; mf < 2; ++mf) {
        int mrow = wave * 32 + mf * 16 + (lane >> 4) * 4;
        #pragma unroll
        for (int nf = 0; nf < 3; ++nf) {
            int n = (nt0 + nf) * 16 + (lane & 15);
            #pragma unroll
            for (int q = 0; q < 4; ++q)
                Cpart[base + (size_t)(mrow + q) * G3 + n] = acc[mf][nf][q];
        }
    }
}

// ---------------------------------------------------------------------------
// Kernel 2: fused epilogue. grid 256 (wg = batch row b), 512 thr (4 cols/thr).
// Sums 2 K-partials + b_hh + gi (table via topi/alive), gates, writes h fp32
// + hi/lo fp16 A-pack, then logits/argmax/log_softmax/topi (+h_final).
// ---------------------------------------------------------------------------
__global__ __launch_bounds__(512)
void fused_out(const float* __restrict__ hprev, float* __restrict__ hnew,
               const float* __restrict__ Cpart, const float* __restrict__ Gt,
               const float* __restrict__ gi0, const float* __restrict__ b_hh,
               const float* __restrict__ W_out, const float* __restrict__ b_out,
               _Float16* __restrict__ Ah, _Float16* __restrict__ Al,
               const int* __restrict__ topi_in, int* __restrict__ topi_out,
               float* __restrict__ lp, float* __restrict__ hfin, int t) {
    const int b = blockIdx.x;
    const int tid = threadIdx.x;
    __shared__ __align__(16) float sh[Hdim];
    __shared__ float sl[16];
    __shared__ int s_sel;
    __shared__ unsigned long long s_m[4];

    if (t > 0) {
        if (tid < 256) {
            int tp = topi_in[tid];
            unsigned long long m = __ballot(tp == (Odim - 1));
            if ((tid & 63) == 0) s_m[tid >> 6] = m;
        }
        __syncthreads();
        if (tid == 0) {
            int bw = b >> 6, bl = b & 63;
            unsigned long long le =
                s_m[bw] & ((bl == 63) ? ~0ULL : ((1ULL << (bl + 1)) - 1ULL));
            bool dead = (le != 0ULL);
            for (int w = 0; w < bw; ++w) dead = dead || (s_m[w] != 0ULL);
            s_sel = dead ? Odim : topi_in[b];
        }
        __syncthreads();
    }
    const float* gp = (t == 0) ? (gi0 + (size_t)b * G3)
                               : (Gt + (size_t)s_sel * G3);

    const int j0 = tid * 4;   // this thread's 4 h-columns
    float hn[4];
    {
        float gsum[3][4];
        #pragma unroll
        for (int g = 0; g < 3; ++g) {
            f4 s = *(const f4*)(b_hh + g * Hdim + j0);
            #pragma unroll
            for (int ks = 0; ks < 2; ++ks)
                s += *(const f4*)(Cpart + ((size_t)ks * Bdim + b) * G3 + g * Hdim + j0);
            #pragma unroll
            for (int c = 0; c < 4; ++c) gsum[g][c] = s[c];
        }
        f4 hp = *(const f4*)(hprev + (size_t)b * Hdim + j0);
        f4 gr = *(const f4*)(gp + j0);
        f4 gz = *(const f4*)(gp + Hdim + j0);
        f4 gn = *(const f4*)(gp + 2 * Hdim + j0);
        #pragma unroll
        for (int c = 0; c < 4; ++c) {
            float rr = 1.f / (1.f + expf(-(gr[c] + gsum[0][c])));
            float zz = 1.f / (1.f + expf(-(gz[c] + gsum[1][c])));
            float nn = tanhf(fmaf(rr, gsum[2][c], gn[c]));
            hn[c] = (1.f - zz) * nn + zz * hp[c];
        }
    }
    f4 o0;
    #pragma unroll
    for (int c = 0; c < 4; ++c) o0[c] = hn[c];
    *(f4*)(hnew + (size_t)b * Hdim + j0) = o0;
    {   // hi/lo fp16 A-pack: 4 k-elems j0..j0+3 of frag (mt=b>>4, kb=j0>>5)
        f16x4 vh, vl;
        #pragma unroll
        for (int c = 0; c < 4; ++c) {
            _Float16 hh = (_Float16)hn[c];
            vh[c] = hh;
            vl[c] = (_Float16)(hn[c] - (float)hh);
        }
        int kb = j0 >> 5, q = (j0 >> 3) & 3, e0 = j0 & 7;
        int lane = (b & 15) + 16 * q, mt = b >> 4;
        size_t off = (((size_t)mt * 64 + kb) * 64 + lane) * 8 + e0;
        *(f16x4*)(Ah + off) = vh;
        *(f16x4*)(Al + off) = vl;
    }
    *(f4*)(sh + j0) = o0;
    __syncthreads();

    const int w = tid >> 6, l = tid & 63;
    for (int o = w; o < Odim; o += 8) {
        const float* wo = W_out + (size_t)o * Hdim;
        float s = 0.f;
        #pragma unroll
        for (int i = 0; i < 32; ++i)
            s = fmaf(sh[l + 64 * i], wo[l + 64 * i], s);
        #pragma unroll
        for (int off = 32; off >= 1; off >>= 1)
            s += __shfl_down(s, off);
        if (l == 0) sl[o] = s + b_out[o];
    }
    __syncthreads();
    if (tid == 0) {
        float m = sl[0]; int bi = 0;
        #pragma unroll
        for (int o = 1; o < Odim; ++o)
            if (sl[o] > m) { m = sl[o]; bi = o; }   // strict > = first max
        float ssum = 0.f;
        #pragma unroll
        for (int o = 0; o < Odim; ++o) ssum += expf(sl[o] - m);
        topi_out[b] = bi;
        sl[14] = m + logf(ssum);
    }
    __syncthreads();
    if (tid < Odim)
        lp[(size_t)b * (Tdim * Odim) + (size_t)t * Odim + tid] = sl[tid] - sl[14];
    if (hfin)
        *(f4*)(hfin + (size_t)b * Hdim + j0) = o0;
}

// ---------------------------------------------------------------------------
extern "C" void kernel_launch(void* const* d_in, const int* in_sizes, int n_in,
                              void* d_out, int out_size, void* d_ws, size_t ws_size,
                              hipStream_t stream) {
    const float* enc_hidden = (const float*)d_in[1];
    const float* target     = (const float*)d_in[2];
    const float* W_ih       = (const float*)d_in[3];
    const float* W_hh       = (const float*)d_in[4];
    const float* b_ih       = (const float*)d_in[5];
    const float* b_hh       = (const float*)d_in[6];
    const float* W_out      = (const float*)d_in[7];
    const float* b_out      = (const float*)d_in[8];

    float* out  = (float*)d_out;
    float* lp   = out;
    float* hfin = out + (size_t)Bdim * Tdim * Odim;

    float* ws    = (float*)d_ws;
    float* hb0   = ws;                        // 524288
    float* hb1   = hb0 + 524288;              // 524288
    float* Gt    = hb1 + 524288;              // 92160
    float* gi0   = Gt + 15 * G3;              // 1572864
    float* Cpart = gi0 + (size_t)Bdim * G3;   // 2*1572864 used
    _Float16* Ah = (_Float16*)(Cpart + 4 * (size_t)Bdim * G3);  // 524288 halves
    _Float16* Al = Ah + (size_t)Bdim * Hdim;                    // 524288
    _Float16* Bh = Al + (size_t)Bdim * Hdim;                    // 12582912
    _Float16* Bl = Bh + (size_t)G3 * Hdim;                      // 12582912
    int* topibuf = (int*)(Bl + (size_t)G3 * Hdim);              // 512 ints

    prep_gtable<<<(15 * G3 + 255) / 256, 256, 0, stream>>>(b_ih, W_ih, Gt);
    prep_gi0<<<(Bdim * G3) / 256, 256, 0, stream>>>(b_ih, W_ih, target, gi0);
    prep_Bpack<<<(G3 * 256) / 256, 256, 0, stream>>>(W_hh, Bh, Bl);
    prep_A0<<<(Bdim * 256) / 256, 256, 0, stream>>>(enc_hidden, Ah, Al);

    for (int t = 0; t < Tdim; ++t) {
        float* hnew = (t & 1) ? hb1 : hb0;
        const float* hprev = (t == 0) ? enc_hidden : ((t & 1) ? hb0 : hb1);
        int* tin  = topibuf + ((t + 1) & 1) * 256;
        int* tout = topibuf + (t & 1) * 256;
        gemm_step<<<dim3(128, 2), 512, 0, stream>>>(Ah, Al, Bh, Bl, Cpart);
        fused_out<<<256, 512, 0, stream>>>(hprev, hnew, Cpart, Gt, gi0, b_hh,
                                           W_out, b_out, Ah, Al, tin, tout, lp,
                                           (t == Tdim - 1) ? hfin : nullptr, t);
    }
}